// Round 1
// baseline (205.728 us; speedup 1.0000x reference)
//
#include <hip/hip_runtime.h>
#include <hip/hip_bf16.h>

typedef unsigned short u16;
typedef unsigned int u32;
typedef __attribute__((ext_vector_type(4))) float f32x4;
typedef __attribute__((ext_vector_type(8))) short bf16x8;

__device__ __forceinline__ u16 f2bf(float f) {
    union { float f; u32 u; } v; v.f = f;
    return (u16)((v.u + 0x7FFFu + ((v.u >> 16) & 1u)) >> 16);
}

__device__ __forceinline__ f32x4 mfma16(bf16x8 a, bf16x8 b, f32x4 c) {
    return __builtin_amdgcn_mfma_f32_16x16x32_bf16(a, b, c, 0, 0, 0);
}

#define GLD_LDS16(g, l) __builtin_amdgcn_global_load_lds( \
    (const __attribute__((address_space(1))) void*)(g),   \
    (__attribute__((address_space(3))) void*)(l), 16, 0, 0)

// ---------------- K0: tables ----------------
__global__ void k_tables(const float* __restrict__ decay_raw,
                         float* __restrict__ bias_tab,
                         float* __restrict__ cosT, float* __restrict__ sinT) {
    int i = blockIdx.x * 256 + threadIdx.x;
    if (i < 16 * 2048) {
        int h = i >> 11, dist = i & 2047;
        float dec = log1pf(expf(decay_raw[h]));            // softplus
        bias_tab[i] = -log1pf(dec * log1pf((float)dist));
    }
    if (i < 1024 * 64) {
        int t = i >> 6, j = i & 63;
        float inv = expf(-logf(10000.0f) * (float)j / 64.0f);
        float ang = (float)(1024 + t) * inv;
        cosT[i] = cosf(ang);
        sinT[i] = sinf(ang);
    }
}

// ---------------- K1a: transpose f32 (R x Cc) -> bf16 (Cc x R) ----------------
__global__ __launch_bounds__(256) void k_transpose_bf16(
    const float* __restrict__ src, u16* __restrict__ dst, int R, int Cc) {
    __shared__ float tile[64][65];
    int c0 = blockIdx.x * 64, r0 = blockIdx.y * 64;
    int tid = threadIdx.x;
#pragma unroll
    for (int it = 0; it < 16; ++it) {
        int idx = it * 256 + tid;
        int r = idx >> 6, c = idx & 63;
        tile[r][c] = src[(size_t)(r0 + r) * Cc + c0 + c];
    }
    __syncthreads();
#pragma unroll
    for (int it = 0; it < 16; ++it) {
        int idx = it * 256 + tid;
        int cc = idx >> 6, rr = idx & 63;
        dst[(size_t)(c0 + cc) * R + r0 + rr] = f2bf(tile[rr][cc]);
    }
}

// ---------------- K1b: flat f32 -> bf16 convert (float4 vectorized) ----------------
__global__ void k_convert_bf16(const float4* __restrict__ src, u16* __restrict__ dst, int n4) {
    int i = blockIdx.x * 256 + threadIdx.x;
    if (i >= n4) return;
    float4 v = src[i];
    u32 p0 = (u32)f2bf(v.x) | ((u32)f2bf(v.y) << 16);
    u32 p1 = (u32)f2bf(v.z) | ((u32)f2bf(v.w) << 16);
    uint2 p; p.x = p0; p.y = p1;
    *(uint2*)(dst + (size_t)i * 4) = p;
}

// ---------------- K2/K5: bf16 GEMM, A (MxK) row-major, Bt (NxK) row-major ----------------
template<int BM, int BN, int WRG, int WCG>
__global__ __launch_bounds__(256) void k_gemm_bt(
    const u16* __restrict__ A, const u16* __restrict__ Bt,
    const float* __restrict__ bias, float* __restrict__ C,
    int M, int N, int K) {
    constexpr int BK = 64;
    constexpr int WM = BM / WRG;
    constexpr int WN = BN / WCG;
    constexpr int MR = WM / 16;
    constexpr int NR = WN / 16;
    __shared__ char lds[(BM + BN) * BK * 2];
    char* ldsA = lds;
    char* ldsB = lds + BM * BK * 2;

    const int tid = threadIdx.x;
    const int lane = tid & 63, wid = tid >> 6;
    const int wr = wid / WCG, wc = wid % WCG;
    const int lhi = lane >> 4, llo = lane & 15;
    const int m0 = blockIdx.y * BM, n0 = blockIdx.x * BN;

    f32x4 acc[MR][NR];
#pragma unroll
    for (int m = 0; m < MR; ++m)
#pragma unroll
        for (int n = 0; n < NR; ++n)
            acc[m][n] = f32x4{0.f, 0.f, 0.f, 0.f};

    for (int k0 = 0; k0 < K; k0 += BK) {
        // stage A tile (BM x 64 bf16), 16B/lane, XOR-swizzled source so LDS holds
        // content[row][chunk p] = global[row][p ^ (row&7)]
#pragma unroll
        for (int it = 0; it < (BM * 8) / 256; ++it) {
            int ci = it * 256 + wid * 64 + lane;
            int r = ci >> 3, c = ci & 7;
            int sc = c ^ (r & 7);
            GLD_LDS16(A + (size_t)(m0 + r) * K + k0 + sc * 8,
                      ldsA + (it * 256 + wid * 64) * 16);
        }
#pragma unroll
        for (int it = 0; it < (BN * 8) / 256; ++it) {
            int ci = it * 256 + wid * 64 + lane;
            int r = ci >> 3, c = ci & 7;
            int sc = c ^ (r & 7);
            GLD_LDS16(Bt + (size_t)(n0 + r) * K + k0 + sc * 8,
                      ldsB + (it * 256 + wid * 64) * 16);
        }
        __syncthreads();
#pragma unroll
        for (int kk = 0; kk < BK; kk += 32) {
            bf16x8 af[MR], bfr[NR];
            const int clb = (kk >> 3) + lhi;
#pragma unroll
            for (int m = 0; m < MR; ++m) {
                int row = wr * WM + m * 16 + llo;
                af[m] = *(const bf16x8*)(ldsA + row * 128 + ((clb ^ (row & 7)) << 4));
            }
#pragma unroll
            for (int n = 0; n < NR; ++n) {
                int row = wc * WN + n * 16 + llo;
                bfr[n] = *(const bf16x8*)(ldsB + row * 128 + ((clb ^ (row & 7)) << 4));
            }
#pragma unroll
            for (int m = 0; m < MR; ++m)
#pragma unroll
                for (int n = 0; n < NR; ++n)
                    acc[m][n] = mfma16(af[m], bfr[n], acc[m][n]);
        }
        __syncthreads();
    }
#pragma unroll
    for (int m = 0; m < MR; ++m) {
        int row = m0 + wr * WM + m * 16 + lhi * 4;
#pragma unroll
        for (int n = 0; n < NR; ++n) {
            int col = n0 + wc * WN + n * 16 + llo;
            float bv = bias[col];
#pragma unroll
            for (int j = 0; j < 4; ++j)
                C[(size_t)(row + j) * N + col] = acc[m][n][j] + bv;
        }
    }
}

// ---------------- K3a: RoPE q/k (new tokens) ----------------
__global__ void k_rope_qk(const float* __restrict__ qkv,
                          const float* __restrict__ cosT, const float* __restrict__ sinT,
                          u16* __restrict__ qb, u16* __restrict__ kb,
                          float* __restrict__ out_k) {
    int i = blockIdx.x * 256 + threadIdx.x;       // 16*1024*64
    if (i >= 16 * 1024 * 64) return;
    int j = i & 63;
    int t = (i >> 6) & 1023;
    int h = i >> 16;
    const float* row = qkv + (size_t)t * 6144;
    float q1 = row[h * 128 + j],        q2 = row[h * 128 + j + 64];
    float k1 = row[2048 + h * 128 + j], k2 = row[2048 + h * 128 + j + 64];
    float cv = cosT[t * 64 + j], sv = sinT[t * 64 + j];
    float qo1 = q1 * cv - q2 * sv, qo2 = q1 * sv + q2 * cv;
    float ko1 = k1 * cv - k2 * sv, ko2 = k1 * sv + k2 * cv;
    size_t qoff = ((size_t)h * 1024 + t) * 128 + j;
    qb[qoff] = f2bf(qo1); qb[qoff + 64] = f2bf(qo2);
    size_t koff = ((size_t)h * 2048 + 1024 + t) * 128 + j;
    kb[koff] = f2bf(ko1); kb[koff + 64] = f2bf(ko2);
    out_k[koff] = ko1; out_k[koff + 64] = ko2;
}

// ---------------- K3b: cached K copy ----------------
__global__ void k_copy_cached_k(const float* __restrict__ cached_k,
                                u16* __restrict__ kb, float* __restrict__ out_k) {
    int i = blockIdx.x * 256 + threadIdx.x;       // 16*1024*128
    if (i >= 16 * 1024 * 128) return;
    int d = i & 127, s = (i >> 7) & 1023, h = i >> 17;
    float v = cached_k[i];
    size_t off = ((size_t)h * 2048 + s) * 128 + d;
    out_k[off] = v;
    kb[off] = f2bf(v);
}

// ---------------- K3c: V assemble: out_v f32 + per-head transposed bf16 ----------------
__global__ __launch_bounds__(256) void k_v_assemble(
    const float* __restrict__ cached_v, const float* __restrict__ qkv,
    float* __restrict__ out_v, u16* __restrict__ vt) {
    __shared__ float tile[64][65];
    int s0 = blockIdx.x * 64, d0 = blockIdx.y * 64, h = blockIdx.z;
    int tid = threadIdx.x;
#pragma unroll
    for (int it = 0; it < 16; ++it) {
        int idx = it * 256 + tid;
        int r = idx >> 6, c = idx & 63;
        int s = s0 + r, d = d0 + c;
        float v = (s < 1024)
            ? cached_v[((size_t)h * 1024 + s) * 128 + d]
            : qkv[(size_t)(s - 1024) * 6144 + 4096 + h * 128 + d];
        tile[r][c] = v;
        out_v[((size_t)h * 2048 + s) * 128 + d] = v;
    }
    __syncthreads();
#pragma unroll
    for (int it = 0; it < 16; ++it) {
        int idx = it * 256 + tid;
        int dd = idx >> 6, ss = idx & 63;
        vt[((size_t)h * 128 + d0 + dd) * 2048 + s0 + ss] = f2bf(tile[ss][dd]);
    }
}

// ---------------- K4: flash attention ----------------
__global__ __launch_bounds__(256) void k_attn(
    const u16* __restrict__ qb,   // [16][1024][128]
    const u16* __restrict__ kb,   // [16][2048][128]
    const u16* __restrict__ vt,   // [16][128][2048]
    const float* __restrict__ bias_tab, // [16][2048]
    u16* __restrict__ yb) {       // [1024][2048]
    __shared__ char ldsK[64 * 256];
    __shared__ char ldsV[128 * 128];
    __shared__ float ldsBias[2048];
    __shared__ u16 ldsP[4][16 * 72];

    const int bid = blockIdx.x;
    const int work = (bid & 7) * 32 + (bid >> 3);   // XCD swizzle: 2 heads per XCD
    const int h = work >> 4, qt = work & 15;
    const int qbase = qt * 64;
    const int tid = threadIdx.x, lane = tid & 63, wid = tid >> 6;
    const int lhi = lane >> 4, llo = lane & 15;

    for (int i = tid; i < 2048; i += 256)
        ldsBias[i] = bias_tab[h * 2048 + i];

    bf16x8 qf[4];
    {
        const u16* qrow = qb + ((size_t)h * 1024 + qbase + wid * 16 + llo) * 128;
#pragma unroll
        for (int c = 0; c < 4; ++c)
            qf[c] = *(const bf16x8*)(qrow + c * 32 + lhi * 8);
    }

    f32x4 acc[8];
#pragma unroll
    for (int d = 0; d < 8; ++d) acc[d] = f32x4{0.f, 0.f, 0.f, 0.f};
    float mrow[4] = {-3e38f, -3e38f, -3e38f, -3e38f};
    float lrow[4] = {0.f, 0.f, 0.f, 0.f};

    const int ntiles = 17 + qt;                    // skip fully-masked s-tiles
    const u16* kg = kb + (size_t)h * 2048 * 128;
    const u16* vg = vt + (size_t)h * 128 * 2048;
    const float scale = 0.08838834764831845f;      // 1/sqrt(128)

    for (int st = 0; st < ntiles; ++st) {
        const int sbase = st * 64;
        __syncthreads();
        // K tile: 64 keys x 128 d (rows of 256B = 16 chunks), swizzled source
#pragma unroll
        for (int it = 0; it < 4; ++it) {
            int ci = it * 256 + wid * 64 + lane;
            int r = ci >> 4, c = ci & 15;
            int sc = c ^ (r & 7);
            GLD_LDS16(kg + (size_t)(sbase + r) * 128 + sc * 8,
                      ldsK + (it * 256 + wid * 64) * 16);
        }
        // V tile (transposed source): 128 d x 64 keys (rows of 128B = 8 chunks)
#pragma unroll
        for (int it = 0; it < 4; ++it) {
            int ci = it * 256 + wid * 64 + lane;
            int r = ci >> 3, c = ci & 7;
            int sc = c ^ (r & 7);
            GLD_LDS16(vg + (size_t)r * 2048 + sbase + sc * 8,
                      ldsV + (it * 256 + wid * 64) * 16);
        }
        __syncthreads();

        // QK^T: 4 key-subtiles of 16
        f32x4 sc4[4];
#pragma unroll
        for (int sub = 0; sub < 4; ++sub) {
            f32x4 s4 = f32x4{0.f, 0.f, 0.f, 0.f};
            int key = sub * 16 + llo;
#pragma unroll
            for (int c2 = 0; c2 < 4; ++c2) {
                int cl = c2 * 4 + lhi;
                bf16x8 kf = *(const bf16x8*)(ldsK + key * 256 + ((cl ^ (key & 7)) << 4));
                s4 = mfma16(qf[c2], kf, s4);
            }
            sc4[sub] = s4;
        }

        // bias + causal mask; row-max
        float pmax[4] = {-3e38f, -3e38f, -3e38f, -3e38f};
#pragma unroll
        for (int sub = 0; sub < 4; ++sub) {
            int key = sbase + sub * 16 + llo;
#pragma unroll
            for (int j = 0; j < 4; ++j) {
                int dist = 1024 + qbase + wid * 16 + lhi * 4 + j - key;
                float v = (dist < 0) ? -3e38f : sc4[sub][j] * scale + ldsBias[dist];
                sc4[sub][j] = v;
                pmax[j] = fmaxf(pmax[j], v);
            }
        }
#pragma unroll
        for (int j = 0; j < 4; ++j) {
            float t = pmax[j];
            t = fmaxf(t, __shfl_xor(t, 1));
            t = fmaxf(t, __shfl_xor(t, 2));
            t = fmaxf(t, __shfl_xor(t, 4));
            t = fmaxf(t, __shfl_xor(t, 8));
            pmax[j] = t;
        }
        float fs[4], psum[4];
#pragma unroll
        for (int j = 0; j < 4; ++j) {
            float mnew = fmaxf(mrow[j], pmax[j]);
            fs[j] = __expf(mrow[j] - mnew);
            mrow[j] = mnew;
            psum[j] = 0.f;
        }
#pragma unroll
        for (int sub = 0; sub < 4; ++sub)
#pragma unroll
            for (int j = 0; j < 4; ++j) {
                float p = __expf(sc4[sub][j] - mrow[j]);
                sc4[sub][j] = p;
                psum[j] += p;
            }
#pragma unroll
        for (int j = 0; j < 4; ++j) {
            float t = psum[j];
            t += __shfl_xor(t, 1);
            t += __shfl_xor(t, 2);
            t += __shfl_xor(t, 4);
            t += __shfl_xor(t, 8);
            lrow[j] = lrow[j] * fs[j] + t;
        }
#pragma unroll
        for (int d = 0; d < 8; ++d)
#pragma unroll
            for (int j = 0; j < 4; ++j)
                acc[d][j] *= fs[j];

        // P -> LDS (per-wave, pitch 72 u16), then PV
        u16* P = &ldsP[wid][0];
#pragma unroll
        for (int sub = 0; sub < 4; ++sub)
#pragma unroll
            for (int j = 0; j < 4; ++j)
                P[(lhi * 4 + j) * 72 + sub * 16 + llo] = f2bf(sc4[sub][j]);

#pragma unroll
        for (int c = 0; c < 2; ++c) {
            bf16x8 pf = *(const bf16x8*)((const char*)P + llo * 144 + c * 64 + lhi * 16);
#pragma unroll
            for (int db = 0; db < 8; ++db) {
                int dr = db * 16 + llo;
                int cl = c * 4 + lhi;
                bf16x8 vf = *(const bf16x8*)(ldsV + dr * 128 + ((cl ^ (dr & 7)) << 4));
                acc[db] = mfma16(pf, vf, acc[db]);
            }
        }
    }
#pragma unroll
    for (int db = 0; db < 8; ++db) {
#pragma unroll
        for (int j = 0; j < 4; ++j) {
            int t = qbase + wid * 16 + lhi * 4 + j;
            float y = acc[db][j] / lrow[j];
            yb[(size_t)t * 2048 + h * 128 + db * 16 + llo] = f2bf(y);
        }
    }
}

// ---------------- launch ----------------
extern "C" void kernel_launch(void* const* d_in, const int* in_sizes, int n_in,
                              void* d_out, int out_size, void* d_ws, size_t ws_size,
                              hipStream_t stream) {
    (void)in_sizes; (void)n_in; (void)out_size;
    const float* x         = (const float*)d_in[0];
    const float* cached_k  = (const float*)d_in[1];
    const float* cached_v  = (const float*)d_in[2];
    const float* W_attn    = (const float*)d_in[3];
    const float* b_attn    = (const float*)d_in[4];
    const float* W_proj    = (const float*)d_in[5];
    const float* b_proj    = (const float*)d_in[6];
    const float* decay_raw = (const float*)d_in[7];

    float* out_y = (float*)d_out;                  // 1024*2048
    float* out_k = out_y + 2097152;                // 16*2048*128
    float* out_v = out_y + 6291456;                // 16*2048*128

    char* ws = (char*)d_ws;
    if (ws_size < 63569920) return;
    u16*   WaT = (u16*)(ws);                       // 6144x2048 bf16   25165824 B
    u16*   WpT = (u16*)(ws + 25165824);            // 2048x2048 bf16    8388608 B
    u16*   Xb  = (u16*)(ws + 33554432);            // 1024x2048 bf16    4194304 B
    float* QKV = (float*)(ws + 37748736);          // 1024x6144 f32    25165824 B
    float* BT  = (float*)(ws + 62914560);          // 16x2048 f32        131072 B
    float* CT  = (float*)(ws + 63045632);          // 1024x64 f32        262144 B
    float* ST  = (float*)(ws + 63307776);          // 1024x64 f32        262144 B
    // aliases into WaT region (dead after QKV GEMM):
    u16* Qb = (u16*)(ws);                          // 16x1024x128 bf16  4194304 B
    u16* Kb = (u16*)(ws + 4194304);                // 16x2048x128 bf16  8388608 B
    u16* Vt = (u16*)(ws + 12582912);               // 16x128x2048 bf16  8388608 B
    u16* Yb = Xb;                                  // alias (Xb dead after QKV GEMM)

    k_tables<<<256, 256, 0, stream>>>(decay_raw, BT, CT, ST);
    k_transpose_bf16<<<dim3(96, 32), 256, 0, stream>>>(W_attn, WaT, 2048, 6144);
    k_transpose_bf16<<<dim3(32, 32), 256, 0, stream>>>(W_proj, WpT, 2048, 2048);
    k_convert_bf16<<<2048, 256, 0, stream>>>((const float4*)x, Xb, 524288);
    k_gemm_bt<128, 128, 2, 2><<<dim3(48, 8), 256, 0, stream>>>(Xb, WaT, b_attn, QKV, 1024, 6144, 2048);
    k_rope_qk<<<4096, 256, 0, stream>>>(QKV, CT, ST, Qb, Kb, out_k);
    k_copy_cached_k<<<8192, 256, 0, stream>>>(cached_k, Kb, out_k);
    k_v_assemble<<<dim3(32, 2, 16), 256, 0, stream>>>(cached_v, QKV, out_v, Vt);
    k_attn<<<256, 256, 0, stream>>>(Qb, Kb, Vt, BT, Yb);
    k_gemm_bt<64, 128, 1, 4><<<dim3(16, 16), 256, 0, stream>>>(Yb, WpT, b_proj, out_y, 1024, 2048, 2048);
}

// Round 2
// 174.358 us; speedup vs baseline: 1.1799x; 1.1799x over previous
//
#include <hip/hip_runtime.h>
#include <hip/hip_bf16.h>

typedef unsigned short u16;
typedef unsigned int u32;
typedef __attribute__((ext_vector_type(4))) float f32x4;
typedef __attribute__((ext_vector_type(8))) short bf16x8;

__device__ __forceinline__ u16 f2bf(float f) {
    union { float f; u32 u; } v; v.f = f;
    return (u16)((v.u + 0x7FFFu + ((v.u >> 16) & 1u)) >> 16);
}
__device__ __forceinline__ float bf2f(u16 b) {
    union { u32 u; float f; } v; v.u = ((u32)b) << 16;
    return v.f;
}

__device__ __forceinline__ f32x4 mfma16(bf16x8 a, bf16x8 b, f32x4 c) {
    return __builtin_amdgcn_mfma_f32_16x16x32_bf16(a, b, c, 0, 0, 0);
}

#define GLD_LDS16(g, l) __builtin_amdgcn_global_load_lds( \
    (const __attribute__((address_space(1))) void*)(g),   \
    (__attribute__((address_space(3))) void*)(l), 16, 0, 0)

// ---------------- K0: tables ----------------
__global__ void k_tables(const float* __restrict__ decay_raw,
                         float* __restrict__ bias_tab,
                         float* __restrict__ cosT, float* __restrict__ sinT) {
    int i = blockIdx.x * 256 + threadIdx.x;
    if (i < 16 * 2048) {
        int h = i >> 11, dist = i & 2047;
        float dec = log1pf(expf(decay_raw[h]));            // softplus
        bias_tab[i] = -log1pf(dec * log1pf((float)dist));
    }
    if (i < 1024 * 64) {
        int t = i >> 6, j = i & 63;
        float inv = expf(-logf(10000.0f) * (float)j / 64.0f);
        float ang = (float)(1024 + t) * inv;
        cosT[i] = cosf(ang);
        sinT[i] = sinf(ang);
    }
}

// ---------------- K1a: transpose f32 (R x Cc) -> bf16 (Cc x R) ----------------
__global__ __launch_bounds__(256) void k_transpose_bf16(
    const float* __restrict__ src, u16* __restrict__ dst, int R, int Cc) {
    __shared__ float tile[64][65];
    int c0 = blockIdx.x * 64, r0 = blockIdx.y * 64;
    int tid = threadIdx.x;
#pragma unroll
    for (int it = 0; it < 16; ++it) {
        int idx = it * 256 + tid;
        int r = idx >> 6, c = idx & 63;
        tile[r][c] = src[(size_t)(r0 + r) * Cc + c0 + c];
    }
    __syncthreads();
#pragma unroll
    for (int it = 0; it < 16; ++it) {
        int idx = it * 256 + tid;
        int cc = idx >> 6, rr = idx & 63;
        dst[(size_t)(c0 + cc) * R + r0 + rr] = f2bf(tile[rr][cc]);
    }
}

// ---------------- K1b: flat f32 -> bf16 convert ----------------
__global__ void k_convert_bf16(const float4* __restrict__ src, u16* __restrict__ dst, int n4) {
    int i = blockIdx.x * 256 + threadIdx.x;
    if (i >= n4) return;
    float4 v = src[i];
    u32 p0 = (u32)f2bf(v.x) | ((u32)f2bf(v.y) << 16);
    u32 p1 = (u32)f2bf(v.z) | ((u32)f2bf(v.w) << 16);
    uint2 p; p.x = p0; p.y = p1;
    *(uint2*)(dst + (size_t)i * 4) = p;
}

// ---------------- K2/K5: bf16 GEMM, A (MxK) row-major, Bt (NxK) row-major ----------------
template<int BM, int BN, int WRG, int WCG>
__global__ __launch_bounds__(256) void k_gemm_bt(
    const u16* __restrict__ A, const u16* __restrict__ Bt,
    const float* __restrict__ bias, float* __restrict__ C,
    int M, int N, int K) {
    constexpr int BK = 64;
    constexpr int WM = BM / WRG;
    constexpr int WN = BN / WCG;
    constexpr int MR = WM / 16;
    constexpr int NR = WN / 16;
    __shared__ char lds[(BM + BN) * BK * 2];
    char* ldsA = lds;
    char* ldsB = lds + BM * BK * 2;

    const int tid = threadIdx.x;
    const int lane = tid & 63, wid = tid >> 6;
    const int wr = wid / WCG, wc = wid % WCG;
    const int lhi = lane >> 4, llo = lane & 15;
    const int m0 = blockIdx.y * BM, n0 = blockIdx.x * BN;

    f32x4 acc[MR][NR];
#pragma unroll
    for (int m = 0; m < MR; ++m)
#pragma unroll
        for (int n = 0; n < NR; ++n)
            acc[m][n] = f32x4{0.f, 0.f, 0.f, 0.f};

    for (int k0 = 0; k0 < K; k0 += BK) {
#pragma unroll
        for (int it = 0; it < (BM * 8) / 256; ++it) {
            int ci = it * 256 + wid * 64 + lane;
            int r = ci >> 3, c = ci & 7;
            int sc = c ^ (r & 7);
            GLD_LDS16(A + (size_t)(m0 + r) * K + k0 + sc * 8,
                      ldsA + (it * 256 + wid * 64) * 16);
        }
#pragma unroll
        for (int it = 0; it < (BN * 8) / 256; ++it) {
            int ci = it * 256 + wid * 64 + lane;
            int r = ci >> 3, c = ci & 7;
            int sc = c ^ (r & 7);
            GLD_LDS16(Bt + (size_t)(n0 + r) * K + k0 + sc * 8,
                      ldsB + (it * 256 + wid * 64) * 16);
        }
        __syncthreads();
#pragma unroll
        for (int kk = 0; kk < BK; kk += 32) {
            bf16x8 af[MR], bfr[NR];
            const int clb = (kk >> 3) + lhi;
#pragma unroll
            for (int m = 0; m < MR; ++m) {
                int row = wr * WM + m * 16 + llo;
                af[m] = *(const bf16x8*)(ldsA + row * 128 + ((clb ^ (row & 7)) << 4));
            }
#pragma unroll
            for (int n = 0; n < NR; ++n) {
                int row = wc * WN + n * 16 + llo;
                bfr[n] = *(const bf16x8*)(ldsB + row * 128 + ((clb ^ (row & 7)) << 4));
            }
#pragma unroll
            for (int m = 0; m < MR; ++m)
#pragma unroll
                for (int n = 0; n < NR; ++n)
                    acc[m][n] = mfma16(af[m], bfr[n], acc[m][n]);
        }
        __syncthreads();
    }
#pragma unroll
    for (int m = 0; m < MR; ++m) {
        int row = m0 + wr * WM + m * 16 + lhi * 4;
#pragma unroll
        for (int n = 0; n < NR; ++n) {
            int col = n0 + wc * WN + n * 16 + llo;
            float bv = bias[col];
#pragma unroll
            for (int j = 0; j < 4; ++j)
                C[(size_t)(row + j) * N + col] = acc[m][n][j] + bv;
        }
    }
}

// ---------------- K3a: RoPE q/k (new tokens) ----------------
__global__ void k_rope_qk(const float* __restrict__ qkv,
                          const float* __restrict__ cosT, const float* __restrict__ sinT,
                          u16* __restrict__ qb, u16* __restrict__ kb,
                          float* __restrict__ out_k) {
    int i = blockIdx.x * 256 + threadIdx.x;       // 16*1024*64
    if (i >= 16 * 1024 * 64) return;
    int j = i & 63;
    int t = (i >> 6) & 1023;
    int h = i >> 16;
    const float* row = qkv + (size_t)t * 6144;
    float q1 = row[h * 128 + j],        q2 = row[h * 128 + j + 64];
    float k1 = row[2048 + h * 128 + j], k2 = row[2048 + h * 128 + j + 64];
    float cv = cosT[t * 64 + j], sv = sinT[t * 64 + j];
    float qo1 = q1 * cv - q2 * sv, qo2 = q1 * sv + q2 * cv;
    float ko1 = k1 * cv - k2 * sv, ko2 = k1 * sv + k2 * cv;
    size_t qoff = ((size_t)h * 1024 + t) * 128 + j;
    qb[qoff] = f2bf(qo1); qb[qoff + 64] = f2bf(qo2);
    size_t koff = ((size_t)h * 2048 + 1024 + t) * 128 + j;
    kb[koff] = f2bf(ko1); kb[koff + 64] = f2bf(ko2);
    out_k[koff] = ko1; out_k[koff + 64] = ko2;
}

// ---------------- K3b: cached K copy ----------------
__global__ void k_copy_cached_k(const float* __restrict__ cached_k,
                                u16* __restrict__ kb, float* __restrict__ out_k) {
    int i = blockIdx.x * 256 + threadIdx.x;       // 16*1024*128
    if (i >= 16 * 1024 * 128) return;
    int d = i & 127, s = (i >> 7) & 1023, h = i >> 17;
    float v = cached_k[i];
    size_t off = ((size_t)h * 2048 + s) * 128 + d;
    out_k[off] = v;
    kb[off] = f2bf(v);
}

// ---------------- K3c: V assemble ----------------
__global__ __launch_bounds__(256) void k_v_assemble(
    const float* __restrict__ cached_v, const float* __restrict__ qkv,
    float* __restrict__ out_v, u16* __restrict__ vt) {
    __shared__ float tile[64][65];
    int s0 = blockIdx.x * 64, d0 = blockIdx.y * 64, h = blockIdx.z;
    int tid = threadIdx.x;
#pragma unroll
    for (int it = 0; it < 16; ++it) {
        int idx = it * 256 + tid;
        int r = idx >> 6, c = idx & 63;
        int s = s0 + r, d = d0 + c;
        float v = (s < 1024)
            ? cached_v[((size_t)h * 1024 + s) * 128 + d]
            : qkv[(size_t)(s - 1024) * 6144 + 4096 + h * 128 + d];
        tile[r][c] = v;
        out_v[((size_t)h * 2048 + s) * 128 + d] = v;
    }
    __syncthreads();
#pragma unroll
    for (int it = 0; it < 16; ++it) {
        int idx = it * 256 + tid;
        int dd = idx >> 6, ss = idx & 63;
        vt[((size_t)h * 128 + d0 + dd) * 2048 + s0 + ss] = f2bf(tile[ss][dd]);
    }
}

// ---------------- K4: flash attention, split-S partials ----------------
__global__ __launch_bounds__(256) void k_attn(
    const u16* __restrict__ qb,   // [16][1024][128]
    const u16* __restrict__ kb,   // [16][2048][128]
    const u16* __restrict__ vt,   // [16][128][2048]
    const float* __restrict__ bias_tab, // [16][2048]
    u16* __restrict__ Pacc,       // [1024 slots][64][128] bf16
    float* __restrict__ Pm,       // [1024 slots][64]
    float* __restrict__ Pl) {     // [1024 slots][64]
    __shared__ char ldsK[64 * 256];
    __shared__ char ldsV[128 * 128];
    __shared__ float ldsBias[2048];
    __shared__ u16 ldsP[4][16 * 68];   // pitch 68 u16: rows hit disjoint bank quads

    const int bid = blockIdx.x;
    const int xcd = bid & 7, idx = bid >> 3;
    const int work = xcd * 128 + idx;              // 2 heads per XCD
    const int h = work >> 6, rem = work & 63;
    const int qt = rem >> 2, chunk = rem & 3;
    const int qbase = qt * 64;
    const int tid = threadIdx.x, lane = tid & 63, wid = tid >> 6;
    const int lhi = lane >> 4, llo = lane & 15;
    const int slot = (h * 16 + qt) * 4 + chunk;

    for (int i = tid; i < 2048; i += 256)
        ldsBias[i] = bias_tab[h * 2048 + i];

    bf16x8 qf[4];
    {
        const u16* qrow = qb + ((size_t)h * 1024 + qbase + wid * 16 + llo) * 128;
#pragma unroll
        for (int c = 0; c < 4; ++c)
            qf[c] = *(const bf16x8*)(qrow + c * 32 + lhi * 8);
    }

    f32x4 acc[8];
#pragma unroll
    for (int d = 0; d < 8; ++d) acc[d] = f32x4{0.f, 0.f, 0.f, 0.f};
    float mrow[4] = {-3e38f, -3e38f, -3e38f, -3e38f};
    float lrow[4] = {0.f, 0.f, 0.f, 0.f};

    const int ntiles = 17 + qt;                    // tiles of 64 keys, causal-clipped
    const u16* kg = kb + (size_t)h * 2048 * 128;
    const u16* vg = vt + (size_t)h * 128 * 2048;
    const float scale = 0.08838834764831845f;      // 1/sqrt(128)

    for (int st = chunk; st < ntiles; st += 4) {
        const int sbase = st * 64;
        __syncthreads();
#pragma unroll
        for (int it = 0; it < 4; ++it) {
            int ci = it * 256 + wid * 64 + lane;
            int r = ci >> 4, c = ci & 15;
            int sc = c ^ (r & 7);
            GLD_LDS16(kg + (size_t)(sbase + r) * 128 + sc * 8,
                      ldsK + (it * 256 + wid * 64) * 16);
        }
#pragma unroll
        for (int it = 0; it < 4; ++it) {
            int ci = it * 256 + wid * 64 + lane;
            int r = ci >> 3, c = ci & 7;
            int sc = c ^ (r & 7);
            GLD_LDS16(vg + (size_t)r * 2048 + sbase + sc * 8,
                      ldsV + (it * 256 + wid * 64) * 16);
        }
        __syncthreads();

        // QK^T
        f32x4 sc4[4];
#pragma unroll
        for (int sub = 0; sub < 4; ++sub) {
            f32x4 s4 = f32x4{0.f, 0.f, 0.f, 0.f};
            int key = sub * 16 + llo;
#pragma unroll
            for (int c2 = 0; c2 < 4; ++c2) {
                int cl = c2 * 4 + lhi;
                bf16x8 kf = *(const bf16x8*)(ldsK + key * 256 + ((cl ^ (key & 7)) << 4));
                s4 = mfma16(qf[c2], kf, s4);
            }
            sc4[sub] = s4;
        }

        // bias + causal mask; row-max
        float pmax[4] = {-3e38f, -3e38f, -3e38f, -3e38f};
#pragma unroll
        for (int sub = 0; sub < 4; ++sub) {
            int key = sbase + sub * 16 + llo;
#pragma unroll
            for (int j = 0; j < 4; ++j) {
                int dist = 1024 + qbase + wid * 16 + lhi * 4 + j - key;
                float v = (dist < 0) ? -3e38f : sc4[sub][j] * scale + ldsBias[dist];
                sc4[sub][j] = v;
                pmax[j] = fmaxf(pmax[j], v);
            }
        }
#pragma unroll
        for (int j = 0; j < 4; ++j) {
            float t = pmax[j];
            t = fmaxf(t, __shfl_xor(t, 1));
            t = fmaxf(t, __shfl_xor(t, 2));
            t = fmaxf(t, __shfl_xor(t, 4));
            t = fmaxf(t, __shfl_xor(t, 8));
            pmax[j] = t;
        }
        float fs[4], psum[4];
#pragma unroll
        for (int j = 0; j < 4; ++j) {
            float mnew = fmaxf(mrow[j], pmax[j]);
            fs[j] = __expf(mrow[j] - mnew);
            mrow[j] = mnew;
            psum[j] = 0.f;
        }
#pragma unroll
        for (int sub = 0; sub < 4; ++sub)
#pragma unroll
            for (int j = 0; j < 4; ++j) {
                float p = __expf(sc4[sub][j] - mrow[j]);
                sc4[sub][j] = p;
                psum[j] += p;
            }
#pragma unroll
        for (int j = 0; j < 4; ++j) {
            float t = psum[j];
            t += __shfl_xor(t, 1);
            t += __shfl_xor(t, 2);
            t += __shfl_xor(t, 4);
            t += __shfl_xor(t, 8);
            lrow[j] = lrow[j] * fs[j] + t;
        }
#pragma unroll
        for (int d = 0; d < 8; ++d)
#pragma unroll
            for (int j = 0; j < 4; ++j)
                acc[d][j] *= fs[j];

        // P -> LDS (per-wave, pitch 68 u16), then PV
        u16* P = &ldsP[wid][0];
#pragma unroll
        for (int sub = 0; sub < 4; ++sub)
#pragma unroll
            for (int j = 0; j < 4; ++j)
                P[(lhi * 4 + j) * 68 + sub * 16 + llo] = f2bf(sc4[sub][j]);

#pragma unroll
        for (int c = 0; c < 2; ++c) {
            bf16x8 pf = *(const bf16x8*)((const char*)P + llo * 136 + c * 64 + lhi * 16);
#pragma unroll
            for (int db = 0; db < 8; ++db) {
                int dr = db * 16 + llo;
                int cl = c * 4 + lhi;
                bf16x8 vf = *(const bf16x8*)(ldsV + dr * 128 + ((cl ^ (dr & 7)) << 4));
                acc[db] = mfma16(pf, vf, acc[db]);
            }
        }
    }

    // write partials
    if (llo == 0) {
#pragma unroll
        for (int j = 0; j < 4; ++j) {
            int r = wid * 16 + lhi * 4 + j;
            Pm[(size_t)slot * 64 + r] = mrow[j];
            Pl[(size_t)slot * 64 + r] = lrow[j];
        }
    }
#pragma unroll
    for (int db = 0; db < 8; ++db)
#pragma unroll
        for (int j = 0; j < 4; ++j) {
            int r = wid * 16 + lhi * 4 + j;
            Pacc[(size_t)slot * 8192 + r * 128 + db * 16 + llo] = f2bf(acc[db][j]);
        }
}

// ---------------- K4b: merge split-S partials ----------------
__global__ __launch_bounds__(256) void k_merge(
    const u16* __restrict__ Pacc, const float* __restrict__ Pm,
    const float* __restrict__ Pl, u16* __restrict__ yb) {
    const int h = blockIdx.x >> 4, qt = blockIdx.x & 15;
    const int slot0 = blockIdx.x * 4;
    const int tid = threadIdx.x;
    const int r = tid >> 2, d0 = (tid & 3) * 32;

    float m[4], l[4];
#pragma unroll
    for (int c = 0; c < 4; ++c) {
        m[c] = Pm[(size_t)(slot0 + c) * 64 + r];
        l[c] = Pl[(size_t)(slot0 + c) * 64 + r];
    }
    float M = fmaxf(fmaxf(m[0], m[1]), fmaxf(m[2], m[3]));
    float w[4], L = 0.f;
#pragma unroll
    for (int c = 0; c < 4; ++c) {
        w[c] = __expf(m[c] - M);
        L += w[c] * l[c];
    }
    float inv = 1.0f / L;

    float y[32];
#pragma unroll
    for (int i = 0; i < 32; ++i) y[i] = 0.f;
#pragma unroll
    for (int c = 0; c < 4; ++c) {
        const uint4* pa = (const uint4*)(Pacc + (size_t)(slot0 + c) * 8192 + r * 128 + d0);
        float wc = w[c];
#pragma unroll
        for (int q = 0; q < 4; ++q) {
            uint4 v = pa[q];
            u32 a[4] = {v.x, v.y, v.z, v.w};
#pragma unroll
            for (int p = 0; p < 4; ++p) {
                y[q * 8 + p * 2]     += wc * bf2f((u16)(a[p] & 0xFFFF));
                y[q * 8 + p * 2 + 1] += wc * bf2f((u16)(a[p] >> 16));
            }
        }
    }
    int trow = qt * 64 + r;
    uint4 outv[4];
    u32* ow = (u32*)outv;
#pragma unroll
    for (int k = 0; k < 16; ++k)
        ow[k] = (u32)f2bf(y[2 * k] * inv) | ((u32)f2bf(y[2 * k + 1] * inv) << 16);
    uint4* dst = (uint4*)(yb + (size_t)trow * 2048 + h * 128 + d0);
#pragma unroll
    for (int q = 0; q < 4; ++q) dst[q] = outv[q];
}

// ---------------- launch ----------------
extern "C" void kernel_launch(void* const* d_in, const int* in_sizes, int n_in,
                              void* d_out, int out_size, void* d_ws, size_t ws_size,
                              hipStream_t stream) {
    (void)in_sizes; (void)n_in; (void)out_size;
    const float* x         = (const float*)d_in[0];
    const float* cached_k  = (const float*)d_in[1];
    const float* cached_v  = (const float*)d_in[2];
    const float* W_attn    = (const float*)d_in[3];
    const float* b_attn    = (const float*)d_in[4];
    const float* W_proj    = (const float*)d_in[5];
    const float* b_proj    = (const float*)d_in[6];
    const float* decay_raw = (const float*)d_in[7];

    float* out_y = (float*)d_out;                  // 1024*2048
    float* out_k = out_y + 2097152;                // 16*2048*128
    float* out_v = out_y + 6291456;                // 16*2048*128

    char* ws = (char*)d_ws;
    if (ws_size < 63569920) return;
    u16*   WaT = (u16*)(ws);                       // 6144x2048 bf16   25165824 B
    u16*   WpT = (u16*)(ws + 25165824);            // 2048x2048 bf16    8388608 B
    u16*   Xb  = (u16*)(ws + 33554432);            // 1024x2048 bf16    4194304 B
    float* QKV = (float*)(ws + 37748736);          // 1024x6144 f32    25165824 B
    float* BT  = (float*)(ws + 62914560);          // 16x2048 f32        131072 B
    float* CT  = (float*)(ws + 63045632);          // 1024x64 f32        262144 B
    float* ST  = (float*)(ws + 63307776);          // 1024x64 f32        262144 B
    // aliases into WaT region (dead after QKV GEMM):
    u16* Qb = (u16*)(ws);                          // 16x1024x128 bf16  4194304 B
    u16* Kb = (u16*)(ws + 4194304);                // 16x2048x128 bf16  8388608 B
    u16* Vt = (u16*)(ws + 12582912);               // 16x128x2048 bf16  8388608 B
    u16* Yb = Xb;                                  // alias (Xb dead after QKV GEMM)
    // split-S partials overlay QKV region (dead after rope/v_assemble):
    u16*   Pacc = (u16*)(ws + 37748736);           // 1024x64x128 bf16 16777216 B
    float* Pm   = (float*)(ws + 54525952);         // 1024x64 f32        262144 B
    float* Pl   = (float*)(ws + 54788096);         // 1024x64 f32        262144 B

    k_tables<<<256, 256, 0, stream>>>(decay_raw, BT, CT, ST);
    k_transpose_bf16<<<dim3(96, 32), 256, 0, stream>>>(W_attn, WaT, 2048, 6144);
    k_transpose_bf16<<<dim3(32, 32), 256, 0, stream>>>(W_proj, WpT, 2048, 2048);
    k_convert_bf16<<<2048, 256, 0, stream>>>((const float4*)x, Xb, 524288);
    k_gemm_bt<128, 96, 2, 2><<<dim3(64, 8), 256, 0, stream>>>(Xb, WaT, b_attn, QKV, 1024, 6144, 2048);
    k_rope_qk<<<4096, 256, 0, stream>>>(QKV, CT, ST, Qb, Kb, out_k);
    k_copy_cached_k<<<8192, 256, 0, stream>>>(cached_k, Kb, out_k);
    k_v_assemble<<<dim3(32, 2, 16), 256, 0, stream>>>(cached_v, QKV, out_v, Vt);
    k_attn<<<1024, 256, 0, stream>>>(Qb, Kb, Vt, BT, Pacc, Pm, Pl);
    k_merge<<<256, 256, 0, stream>>>(Pacc, Pm, Pl, Yb);
    k_gemm_bt<64, 64, 2, 2><<<dim3(32, 16), 256, 0, stream>>>(Yb, WpT, b_proj, out_y, 1024, 2048, 2048);
}

// Round 3
// 145.187 us; speedup vs baseline: 1.4170x; 1.2009x over previous
//
#include <hip/hip_runtime.h>
#include <hip/hip_bf16.h>

typedef unsigned short u16;
typedef unsigned int u32;
typedef __attribute__((ext_vector_type(4))) float f32x4;
typedef __attribute__((ext_vector_type(8))) short bf16x8;

__device__ __forceinline__ u16 f2bf(float f) {
    union { float f; u32 u; } v; v.f = f;
    return (u16)((v.u + 0x7FFFu + ((v.u >> 16) & 1u)) >> 16);
}
__device__ __forceinline__ float bf2f(u16 b) {
    union { u32 u; float f; } v; v.u = ((u32)b) << 16;
    return v.f;
}
__device__ __forceinline__ void st_out(float* p, float v) { *p = v; }
__device__ __forceinline__ void st_out(u16* p, float v) { *p = f2bf(v); }

__device__ __forceinline__ f32x4 mfma16(bf16x8 a, bf16x8 b, f32x4 c) {
    return __builtin_amdgcn_mfma_f32_16x16x32_bf16(a, b, c, 0, 0, 0);
}

#define GLD_LDS16(g, l) __builtin_amdgcn_global_load_lds( \
    (const __attribute__((address_space(1))) void*)(g),   \
    (__attribute__((address_space(3))) void*)(l), 16, 0, 0)

// ---------------- K_prep: tables + W transposes + x convert (fused) ----------------
__global__ __launch_bounds__(256) void k_prep(
    const float* __restrict__ W_attn, const float* __restrict__ W_proj,
    const float* __restrict__ x, const float* __restrict__ decay_raw,
    u16* __restrict__ WaT, u16* __restrict__ WpT, u16* __restrict__ Xb,
    float* __restrict__ bias_tab, float* __restrict__ cosT, float* __restrict__ sinT) {
    __shared__ float tile[64][65];
    const int b = blockIdx.x, tid = threadIdx.x;
    if (b < 4096) {
        // transpose f32 (R x Cc) -> bf16 (Cc x R)
        const float* src; u16* dst; int R, Cc, bx, by;
        if (b < 3072) { src = W_attn; dst = WaT; R = 2048; Cc = 6144; bx = b % 96; by = b / 96; }
        else          { src = W_proj; dst = WpT; R = 2048; Cc = 2048; bx = (b - 3072) & 31; by = (b - 3072) >> 5; }
        int c0 = bx * 64, r0 = by * 64;
#pragma unroll
        for (int it = 0; it < 16; ++it) {
            int idx = it * 256 + tid;
            int r = idx >> 6, c = idx & 63;
            tile[r][c] = src[(size_t)(r0 + r) * Cc + c0 + c];
        }
        __syncthreads();
#pragma unroll
        for (int it = 0; it < 16; ++it) {
            int idx = it * 256 + tid;
            int cc = idx >> 6, rr = idx & 63;
            dst[(size_t)(c0 + cc) * R + r0 + rr] = f2bf(tile[rr][cc]);
        }
    } else if (b < 6144) {
        int i = (b - 4096) * 256 + tid;          // 524288 float4s
        float4 v = ((const float4*)x)[i];
        u32 p0 = (u32)f2bf(v.x) | ((u32)f2bf(v.y) << 16);
        u32 p1 = (u32)f2bf(v.z) | ((u32)f2bf(v.w) << 16);
        uint2 p; p.x = p0; p.y = p1;
        *(uint2*)(Xb + (size_t)i * 4) = p;
    } else {
        int i = (b - 6144) * 256 + tid;
        if (i < 16 * 2048) {
            int h = i >> 11, dist = i & 2047;
            float dec = log1pf(expf(decay_raw[h]));
            bias_tab[i] = -log1pf(dec * log1pf((float)dist));
        }
        if (i < 1024 * 64) {
            int t = i >> 6, j = i & 63;
            float inv = expf(-logf(10000.0f) * (float)j / 64.0f);
            float ang = (float)(1024 + t) * inv;
            cosT[i] = cosf(ang);
            sinT[i] = sinf(ang);
        }
    }
}

// ---------------- GEMM: A (MxK) bf16 row-major, Bt (NxK) bf16 row-major ----------------
template<int BM, int BN, int WRG, int WCG, typename OT>
__global__ __launch_bounds__(256) void k_gemm_bt(
    const u16* __restrict__ A, const u16* __restrict__ Bt,
    const float* __restrict__ bias, OT* __restrict__ C,
    int M, int N, int K) {
    constexpr int BK = 64;
    constexpr int WM = BM / WRG;
    constexpr int WN = BN / WCG;
    constexpr int MR = WM / 16;
    constexpr int NR = WN / 16;
    __shared__ char lds[(BM + BN) * BK * 2];
    char* ldsA = lds;
    char* ldsB = lds + BM * BK * 2;

    const int tid = threadIdx.x;
    const int lane = tid & 63, wid = tid >> 6;
    const int wr = wid / WCG, wc = wid % WCG;
    const int lhi = lane >> 4, llo = lane & 15;
    const int m0 = blockIdx.y * BM, n0 = blockIdx.x * BN;

    f32x4 acc[MR][NR];
#pragma unroll
    for (int m = 0; m < MR; ++m)
#pragma unroll
        for (int n = 0; n < NR; ++n)
            acc[m][n] = f32x4{0.f, 0.f, 0.f, 0.f};

    for (int k0 = 0; k0 < K; k0 += BK) {
#pragma unroll
        for (int it = 0; it < (BM * 8) / 256; ++it) {
            int ci = it * 256 + wid * 64 + lane;
            int r = ci >> 3, c = ci & 7;
            int sc = c ^ (r & 7);
            GLD_LDS16(A + (size_t)(m0 + r) * K + k0 + sc * 8,
                      ldsA + (it * 256 + wid * 64) * 16);
        }
#pragma unroll
        for (int it = 0; it < (BN * 8) / 256; ++it) {
            int ci = it * 256 + wid * 64 + lane;
            int r = ci >> 3, c = ci & 7;
            int sc = c ^ (r & 7);
            GLD_LDS16(Bt + (size_t)(n0 + r) * K + k0 + sc * 8,
                      ldsB + (it * 256 + wid * 64) * 16);
        }
        __syncthreads();
#pragma unroll
        for (int kk = 0; kk < BK; kk += 32) {
            bf16x8 af[MR], bfr[NR];
            const int clb = (kk >> 3) + lhi;
#pragma unroll
            for (int m = 0; m < MR; ++m) {
                int row = wr * WM + m * 16 + llo;
                af[m] = *(const bf16x8*)(ldsA + row * 128 + ((clb ^ (row & 7)) << 4));
            }
#pragma unroll
            for (int n = 0; n < NR; ++n) {
                int row = wc * WN + n * 16 + llo;
                bfr[n] = *(const bf16x8*)(ldsB + row * 128 + ((clb ^ (row & 7)) << 4));
            }
#pragma unroll
            for (int m = 0; m < MR; ++m)
#pragma unroll
                for (int n = 0; n < NR; ++n)
                    acc[m][n] = mfma16(af[m], bfr[n], acc[m][n]);
        }
        __syncthreads();
    }
#pragma unroll
    for (int m = 0; m < MR; ++m) {
        int row = m0 + wr * WM + m * 16 + lhi * 4;
#pragma unroll
        for (int n = 0; n < NR; ++n) {
            int col = n0 + wc * WN + n * 16 + llo;
            float bv = bias[col];
#pragma unroll
            for (int j = 0; j < 4; ++j)
                st_out(&C[(size_t)(row + j) * N + col], acc[m][n][j] + bv);
        }
    }
}

// ---------------- K_fuse2: RoPE q/k (bf16 QKV in) + cached K copy ----------------
__global__ void k_fuse2(const u16* __restrict__ qkv,
                        const float* __restrict__ cosT, const float* __restrict__ sinT,
                        const float* __restrict__ cached_k,
                        u16* __restrict__ qb, u16* __restrict__ kb,
                        float* __restrict__ out_k) {
    const int b = blockIdx.x;
    if (b < 4096) {
        int i = b * 256 + threadIdx.x;             // 16*1024*64
        int j = i & 63;
        int t = (i >> 6) & 1023;
        int h = i >> 16;
        const u16* row = qkv + (size_t)t * 6144;
        float q1 = bf2f(row[h * 128 + j]),        q2 = bf2f(row[h * 128 + j + 64]);
        float k1 = bf2f(row[2048 + h * 128 + j]), k2 = bf2f(row[2048 + h * 128 + j + 64]);
        float cv = cosT[t * 64 + j], sv = sinT[t * 64 + j];
        float qo1 = q1 * cv - q2 * sv, qo2 = q1 * sv + q2 * cv;
        float ko1 = k1 * cv - k2 * sv, ko2 = k1 * sv + k2 * cv;
        size_t qoff = ((size_t)h * 1024 + t) * 128 + j;
        qb[qoff] = f2bf(qo1); qb[qoff + 64] = f2bf(qo2);
        size_t koff = ((size_t)h * 2048 + 1024 + t) * 128 + j;
        kb[koff] = f2bf(ko1); kb[koff + 64] = f2bf(ko2);
        out_k[koff] = ko1; out_k[koff + 64] = ko2;
    } else {
        int i = (b - 4096) * 256 + threadIdx.x;    // 16*1024*128
        int d = i & 127, s = (i >> 7) & 1023, h = i >> 17;
        float v = cached_k[i];
        size_t off = ((size_t)h * 2048 + s) * 128 + d;
        out_k[off] = v;
        kb[off] = f2bf(v);
    }
}

// ---------------- K3c: V assemble ----------------
__global__ __launch_bounds__(256) void k_v_assemble(
    const float* __restrict__ cached_v, const u16* __restrict__ qkv,
    float* __restrict__ out_v, u16* __restrict__ vt) {
    __shared__ u16 tile[64][65];
    int s0 = blockIdx.x * 64, d0 = blockIdx.y * 64, h = blockIdx.z;
    int tid = threadIdx.x;
#pragma unroll
    for (int it = 0; it < 16; ++it) {
        int idx = it * 256 + tid;
        int r = idx >> 6, c = idx & 63;
        int s = s0 + r, d = d0 + c;
        u16 v = (s < 1024)
            ? f2bf(cached_v[((size_t)h * 1024 + s) * 128 + d])
            : qkv[(size_t)(s - 1024) * 6144 + 4096 + h * 128 + d];
        tile[r][c] = v;
        out_v[((size_t)h * 2048 + s) * 128 + d] = bf2f(v);
    }
    __syncthreads();
#pragma unroll
    for (int it = 0; it < 16; ++it) {
        int idx = it * 256 + tid;
        int dd = idx >> 6, ss = idx & 63;
        vt[((size_t)h * 128 + d0 + dd) * 2048 + s0 + ss] = tile[ss][dd];
    }
}

// ---------------- K4: flash attention, split-S, dbuf KVBLK=32, defer-max ----------------
__global__ __launch_bounds__(256, 4) void k_attn(
    const u16* __restrict__ qb,   // [16][1024][128]
    const u16* __restrict__ kb,   // [16][2048][128]
    const u16* __restrict__ vt,   // [16][128][2048]
    const float* __restrict__ bias_tab, // [16][2048]
    u16* __restrict__ Pacc,       // [1024 slots][64][128] bf16
    float* __restrict__ Pm,       // [1024 slots][64]
    float* __restrict__ Pl) {     // [1024 slots][64]
    __shared__ char ldsK[2][32 * 256];   // 8 KB each
    __shared__ char ldsV[2][128 * 64];   // 8 KB each
    __shared__ u16 ldsP[4][16 * 36];     // pitch 36 u16

    const int bid = blockIdx.x;
    const int xcd = bid & 7, idx = bid >> 3;
    const int work = xcd * 128 + idx;              // 2 heads per XCD
    const int h = work >> 6, rem = work & 63;
    const int qt = rem >> 2, chunk = rem & 3;
    const int qbase = qt * 64;
    const int tid = threadIdx.x, lane = tid & 63, wid = tid >> 6;
    const int lhi = lane >> 4, llo = lane & 15;
    const int slot = (h * 16 + qt) * 4 + chunk;

    const u16* kg = kb + (size_t)h * 2048 * 128;
    const u16* vg = vt + (size_t)h * 128 * 2048;
    const float* bt = bias_tab + h * 2048;

    bf16x8 qf[4];
    {
        const u16* qrow = qb + ((size_t)h * 1024 + qbase + wid * 16 + llo) * 128;
#pragma unroll
        for (int c = 0; c < 4; ++c)
            qf[c] = *(const bf16x8*)(qrow + c * 32 + lhi * 8);
    }

    f32x4 acc[8];
#pragma unroll
    for (int d = 0; d < 8; ++d) acc[d] = f32x4{0.f, 0.f, 0.f, 0.f};
    float mrow[4] = {-3e38f, -3e38f, -3e38f, -3e38f};
    float lrow[4] = {0.f, 0.f, 0.f, 0.f};

    const int ntiles = 34 + 2 * qt;                // 32-key tiles
    const float scale = 0.08838834764831845f;      // 1/sqrt(128)
    const int qpos = 1024 + qbase + wid * 16 + lhi * 4;

    auto stage = [&](int b, int st) {
        int sbase = st * 32;
#pragma unroll
        for (int it = 0; it < 2; ++it) {           // K: 32 rows x 16 chunks
            int ci = it * 256 + tid;
            int r = ci >> 4, c = ci & 15;
            int sc = c ^ (r & 7);
            GLD_LDS16(kg + (size_t)(sbase + r) * 128 + sc * 8,
                      &ldsK[b][0] + (it * 256 + wid * 64) * 16);
        }
#pragma unroll
        for (int it = 0; it < 2; ++it) {           // V: 128 rows x 4 chunks
            int ci = it * 256 + tid;
            int r = ci >> 2, c = ci & 3;
            int sc = c ^ ((r >> 1) & 3);
            GLD_LDS16(vg + (size_t)r * 2048 + sbase + sc * 8,
                      &ldsV[b][0] + (it * 256 + wid * 64) * 16);
        }
    };

    // descending tile order: near-diagonal (high-bias) first -> few rescales
    const int st0 = chunk + 4 * ((ntiles - 1 - chunk) >> 2);
    stage(0, st0);
    __syncthreads();
    int cur = 0;
    for (int st = st0; st >= chunk; st -= 4) {
        if (st >= chunk + 4) stage(cur ^ 1, st - 4);
        const int sbase = st * 32;
        const char* lK = &ldsK[cur][0];
        const char* lV = &ldsV[cur][0];

        // QK^T: 2 key-subtiles of 16
        f32x4 sc4[2];
#pragma unroll
        for (int sub = 0; sub < 2; ++sub) {
            f32x4 s4 = f32x4{0.f, 0.f, 0.f, 0.f};
            int key = sub * 16 + llo;
#pragma unroll
            for (int c2 = 0; c2 < 4; ++c2) {
                int cl = c2 * 4 + lhi;
                bf16x8 kf = *(const bf16x8*)(lK + key * 256 + ((cl ^ (key & 7)) << 4));
                s4 = mfma16(qf[c2], kf, s4);
            }
            sc4[sub] = s4;
        }

        // bias + causal mask
#pragma unroll
        for (int sub = 0; sub < 2; ++sub) {
            int key = sbase + sub * 16 + llo;
#pragma unroll
            for (int j = 0; j < 4; ++j) {
                int dist = qpos + j - key;
                float bv = bt[dist < 0 ? 0 : dist];
                sc4[sub][j] = (dist < 0) ? -3e38f : sc4[sub][j] * scale + bv;
            }
        }
        // defer-max: only reduce+rescale when a value exceeds mrow + 8
        float tmax[4];
        int ok = 1;
#pragma unroll
        for (int j = 0; j < 4; ++j) {
            tmax[j] = fmaxf(sc4[0][j], sc4[1][j]);
            ok &= (tmax[j] <= mrow[j] + 8.0f) ? 1 : 0;
        }
        if (!__all(ok)) {
#pragma unroll
            for (int j = 0; j < 4; ++j) {
                float t = tmax[j];
                t = fmaxf(t, __shfl_xor(t, 1));
                t = fmaxf(t, __shfl_xor(t, 2));
                t = fmaxf(t, __shfl_xor(t, 4));
                t = fmaxf(t, __shfl_xor(t, 8));
                float mnew = fmaxf(mrow[j], t);
                float fs = __expf(mrow[j] - mnew);
                mrow[j] = mnew;
                lrow[j] *= fs;
#pragma unroll
                for (int d = 0; d < 8; ++d) acc[d][j] *= fs;
            }
        }
        // P = exp(s - m); lrow accumulates PER-LANE partials (reduced at end)
#pragma unroll
        for (int sub = 0; sub < 2; ++sub)
#pragma unroll
            for (int j = 0; j < 4; ++j) {
                float p = __expf(sc4[sub][j] - mrow[j]);
                sc4[sub][j] = p;
                lrow[j] += p;
            }

        // P -> LDS (per-wave), then PV
        u16* P = &ldsP[wid][0];
#pragma unroll
        for (int sub = 0; sub < 2; ++sub)
#pragma unroll
            for (int j = 0; j < 4; ++j)
                P[(lhi * 4 + j) * 36 + sub * 16 + llo] = f2bf(sc4[sub][j]);

        bf16x8 pf = *(const bf16x8*)((const char*)P + llo * 72 + lhi * 16);
#pragma unroll
        for (int db = 0; db < 8; ++db) {
            int dr = db * 16 + llo;
            int cl = lhi ^ ((dr >> 1) & 3);
            bf16x8 vf = *(const bf16x8*)(lV + dr * 64 + cl * 16);
            acc[db] = mfma16(pf, vf, acc[db]);
        }
        __syncthreads();
        cur ^= 1;
    }

    // final sum-reduce of per-lane lrow partials across llo
#pragma unroll
    for (int j = 0; j < 4; ++j) {
        float t = lrow[j];
        t += __shfl_xor(t, 1);
        t += __shfl_xor(t, 2);
        t += __shfl_xor(t, 4);
        t += __shfl_xor(t, 8);
        lrow[j] = t;
    }

    if (llo == 0) {
#pragma unroll
        for (int j = 0; j < 4; ++j) {
            int r = wid * 16 + lhi * 4 + j;
            Pm[(size_t)slot * 64 + r] = mrow[j];
            Pl[(size_t)slot * 64 + r] = lrow[j];
        }
    }
#pragma unroll
    for (int db = 0; db < 8; ++db)
#pragma unroll
        for (int j = 0; j < 4; ++j) {
            int r = wid * 16 + lhi * 4 + j;
            Pacc[(size_t)slot * 8192 + r * 128 + db * 16 + llo] = f2bf(acc[db][j]);
        }
}

// ---------------- K4b: merge split-S partials ----------------
__global__ __launch_bounds__(256) void k_merge(
    const u16* __restrict__ Pacc, const float* __restrict__ Pm,
    const float* __restrict__ Pl, u16* __restrict__ yb) {
    const int h = blockIdx.x >> 4, qt = blockIdx.x & 15;
    const int slot0 = blockIdx.x * 4;
    const int tid = threadIdx.x;
    const int r = tid >> 2, d0 = (tid & 3) * 32;

    float m[4], l[4];
#pragma unroll
    for (int c = 0; c < 4; ++c) {
        m[c] = Pm[(size_t)(slot0 + c) * 64 + r];
        l[c] = Pl[(size_t)(slot0 + c) * 64 + r];
    }
    float M = fmaxf(fmaxf(m[0], m[1]), fmaxf(m[2], m[3]));
    float w[4], L = 0.f;
#pragma unroll
    for (int c = 0; c < 4; ++c) {
        w[c] = __expf(m[c] - M);
        L += w[c] * l[c];
    }
    float inv = 1.0f / L;

    float y[32];
#pragma unroll
    for (int i = 0; i < 32; ++i) y[i] = 0.f;
#pragma unroll
    for (int c = 0; c < 4; ++c) {
        const uint4* pa = (const uint4*)(Pacc + (size_t)(slot0 + c) * 8192 + r * 128 + d0);
        float wc = w[c];
#pragma unroll
        for (int q = 0; q < 4; ++q) {
            uint4 v = pa[q];
            u32 a[4] = {v.x, v.y, v.z, v.w};
#pragma unroll
            for (int p = 0; p < 4; ++p) {
                y[q * 8 + p * 2]     += wc * bf2f((u16)(a[p] & 0xFFFF));
                y[q * 8 + p * 2 + 1] += wc * bf2f((u16)(a[p] >> 16));
            }
        }
    }
    int trow = qt * 64 + r;
    uint4 outv[4];
    u32* ow = (u32*)outv;
#pragma unroll
    for (int k = 0; k < 16; ++k)
        ow[k] = (u32)f2bf(y[2 * k] * inv) | ((u32)f2bf(y[2 * k + 1] * inv) << 16);
    uint4* dst = (uint4*)(yb + (size_t)trow * 2048 + h * 128 + d0);
#pragma unroll
    for (int q = 0; q < 4; ++q) dst[q] = outv[q];
}

// ---------------- launch ----------------
extern "C" void kernel_launch(void* const* d_in, const int* in_sizes, int n_in,
                              void* d_out, int out_size, void* d_ws, size_t ws_size,
                              hipStream_t stream) {
    (void)in_sizes; (void)n_in; (void)out_size;
    const float* x         = (const float*)d_in[0];
    const float* cached_k  = (const float*)d_in[1];
    const float* cached_v  = (const float*)d_in[2];
    const float* W_attn    = (const float*)d_in[3];
    const float* b_attn    = (const float*)d_in[4];
    const float* W_proj    = (const float*)d_in[5];
    const float* b_proj    = (const float*)d_in[6];
    const float* decay_raw = (const float*)d_in[7];

    float* out_y = (float*)d_out;                  // 1024*2048
    float* out_k = out_y + 2097152;                // 16*2048*128
    float* out_v = out_y + 6291456;                // 16*2048*128

    char* ws = (char*)d_ws;
    if (ws_size < 63569920) return;
    // phase-1 regions
    u16*   WaT  = (u16*)(ws);                      // 6144x2048 bf16   25165824 B
    u16*   WpT  = (u16*)(ws + 25165824);           // 2048x2048 bf16    8388608 B (persists)
    u16*   Xb   = (u16*)(ws + 33554432);           // 1024x2048 bf16    4194304 B
    u16*   QKVb = (u16*)(ws + 37748736);           // 1024x6144 bf16   12582912 B
    float* BT   = (float*)(ws + 62914560);         // 16x2048 f32 (persists)
    float* CT   = (float*)(ws + 63045632);         // 1024x64 f32
    float* ST   = (float*)(ws + 63307776);         // 1024x64 f32
    // phase-2 aliases (dead regions reused)
    u16*   Qb   = (u16*)(ws);                      // in WaT   4194304 B
    u16*   Kb   = (u16*)(ws + 4194304);            // in WaT   8388608 B
    u16*   Vt   = (u16*)(ws + 12582912);           // in WaT   8388608 B
    u16*   Yb   = (u16*)(ws + 20971520);           // in WaT   4194304 B
    float* Pm   = (float*)(ws + 33554432);         // in Xb     262144 B
    float* Pl   = (float*)(ws + 33816576);         // in Xb     262144 B
    u16*   Pacc = (u16*)(ws + 37748736);           // over QKVb 16777216 B (to 54525952)

    k_prep<<<6400, 256, 0, stream>>>(W_attn, W_proj, x, decay_raw, WaT, WpT, Xb, BT, CT, ST);
    k_gemm_bt<128, 96, 2, 2, u16><<<dim3(64, 8), 256, 0, stream>>>(Xb, WaT, b_attn, QKVb, 1024, 6144, 2048);
    k_fuse2<<<12288, 256, 0, stream>>>(QKVb, CT, ST, cached_k, Qb, Kb, out_k);
    k_v_assemble<<<dim3(32, 2, 16), 256, 0, stream>>>(cached_v, QKVb, out_v, Vt);
    k_attn<<<1024, 256, 0, stream>>>(Qb, Kb, Vt, BT, Pacc, Pm, Pl);
    k_merge<<<256, 256, 0, stream>>>(Pacc, Pm, Pl, Yb);
    k_gemm_bt<64, 64, 2, 2, float><<<dim3(32, 16), 256, 0, stream>>>(Yb, WpT, b_proj, out_y, 1024, 2048, 2048);
}

// Round 4
// 139.413 us; speedup vs baseline: 1.4757x; 1.0414x over previous
//
#include <hip/hip_runtime.h>
#include <hip/hip_bf16.h>

typedef unsigned short u16;
typedef unsigned int u32;
typedef __attribute__((ext_vector_type(4))) float f32x4;
typedef __attribute__((ext_vector_type(8))) short bf16x8;

__device__ __forceinline__ u16 f2bf(float f) {
    union { float f; u32 u; } v; v.f = f;
    return (u16)((v.u + 0x7FFFu + ((v.u >> 16) & 1u)) >> 16);
}
__device__ __forceinline__ float bf2f(u16 b) {
    union { u32 u; float f; } v; v.u = ((u32)b) << 16;
    return v.f;
}
__device__ __forceinline__ void st_out(float* p, float v) { *p = v; }
__device__ __forceinline__ void st_out(u16* p, float v) { *p = f2bf(v); }

__device__ __forceinline__ f32x4 mfma16(bf16x8 a, bf16x8 b, f32x4 c) {
    return __builtin_amdgcn_mfma_f32_16x16x32_bf16(a, b, c, 0, 0, 0);
}

#define GLD_LDS16(g, l) __builtin_amdgcn_global_load_lds( \
    (const __attribute__((address_space(1))) void*)(g),   \
    (__attribute__((address_space(3))) void*)(l), 16, 0, 0)

// ---------------- K_prep: tables + W transposes + x convert (fused) ----------------
__global__ __launch_bounds__(256) void k_prep(
    const float* __restrict__ W_attn, const float* __restrict__ W_proj,
    const float* __restrict__ x, const float* __restrict__ decay_raw,
    u16* __restrict__ WaT, u16* __restrict__ WpT, u16* __restrict__ Xb,
    float* __restrict__ bias_tab, float* __restrict__ cosT, float* __restrict__ sinT) {
    __shared__ float tile[64][65];
    const int b = blockIdx.x, tid = threadIdx.x;
    if (b < 4096) {
        // transpose f32 (R x Cc) -> bf16 (Cc x R)
        const float* src; u16* dst; int R, Cc, bx, by;
        if (b < 3072) { src = W_attn; dst = WaT; R = 2048; Cc = 6144; bx = b % 96; by = b / 96; }
        else          { src = W_proj; dst = WpT; R = 2048; Cc = 2048; bx = (b - 3072) & 31; by = (b - 3072) >> 5; }
        int c0 = bx * 64, r0 = by * 64;
#pragma unroll
        for (int it = 0; it < 16; ++it) {
            int idx = it * 256 + tid;
            int r = idx >> 6, c = idx & 63;
            tile[r][c] = src[(size_t)(r0 + r) * Cc + c0 + c];
        }
        __syncthreads();
#pragma unroll
        for (int it = 0; it < 16; ++it) {
            int idx = it * 256 + tid;
            int cc = idx >> 6, rr = idx & 63;
            dst[(size_t)(c0 + cc) * R + r0 + rr] = f2bf(tile[rr][cc]);
        }
    } else if (b < 6144) {
        int i = (b - 4096) * 256 + tid;          // 524288 float4s
        float4 v = ((const float4*)x)[i];
        u32 p0 = (u32)f2bf(v.x) | ((u32)f2bf(v.y) << 16);
        u32 p1 = (u32)f2bf(v.z) | ((u32)f2bf(v.w) << 16);
        uint2 p; p.x = p0; p.y = p1;
        *(uint2*)(Xb + (size_t)i * 4) = p;
    } else {
        int i = (b - 6144) * 256 + tid;
        if (i < 16 * 2048) {
            int h = i >> 11, dist = i & 2047;
            float dec = log1pf(expf(decay_raw[h]));
            bias_tab[i] = -log1pf(dec * log1pf((float)dist));
        }
        if (i < 1024 * 64) {
            int t = i >> 6, j = i & 63;
            float inv = expf(-logf(10000.0f) * (float)j / 64.0f);
            float ang = (float)(1024 + t) * inv;
            cosT[i] = cosf(ang);
            sinT[i] = sinf(ang);
        }
    }
}

// ---------------- GEMM: A (MxK) bf16 row-major, Bt (NxK) bf16 row-major ----------------
// Double-buffered 2-phase: stage tile t+1 BEFORE computing tile t, one barrier per tile.
template<int BM, int BN, int WRG, int WCG, typename OT>
__global__ __launch_bounds__(256) void k_gemm_bt(
    const u16* __restrict__ A, const u16* __restrict__ Bt,
    const float* __restrict__ bias, OT* __restrict__ C,
    int M, int N, int K) {
    constexpr int BK = 64;
    constexpr int WM = BM / WRG;
    constexpr int WN = BN / WCG;
    constexpr int MR = WM / 16;
    constexpr int NR = WN / 16;
    constexpr int LDSZ = (BM + BN) * BK * 2;
    __shared__ char lds[2][LDSZ];

    const int tid = threadIdx.x;
    const int lane = tid & 63, wid = tid >> 6;
    const int wr = wid / WCG, wc = wid % WCG;
    const int lhi = lane >> 4, llo = lane & 15;
    const int m0 = blockIdx.y * BM, n0 = blockIdx.x * BN;

    f32x4 acc[MR][NR];
#pragma unroll
    for (int m = 0; m < MR; ++m)
#pragma unroll
        for (int n = 0; n < NR; ++n)
            acc[m][n] = f32x4{0.f, 0.f, 0.f, 0.f};

    auto stage = [&](int buf, int k0) {
        char* ldsA = &lds[buf][0];
        char* ldsB = &lds[buf][0] + BM * BK * 2;
#pragma unroll
        for (int it = 0; it < (BM * 8) / 256; ++it) {
            int ci = it * 256 + wid * 64 + lane;
            int r = ci >> 3, c = ci & 7;
            int sc = c ^ (r & 7);
            GLD_LDS16(A + (size_t)(m0 + r) * K + k0 + sc * 8,
                      ldsA + (it * 256 + wid * 64) * 16);
        }
#pragma unroll
        for (int it = 0; it < (BN * 8) / 256; ++it) {
            int ci = it * 256 + wid * 64 + lane;
            int r = ci >> 3, c = ci & 7;
            int sc = c ^ (r & 7);
            GLD_LDS16(Bt + (size_t)(n0 + r) * K + k0 + sc * 8,
                      ldsB + (it * 256 + wid * 64) * 16);
        }
    };

    stage(0, 0);
    __syncthreads();
    int cur = 0;
    for (int k0 = 0; k0 < K; k0 += BK) {
        if (k0 + BK < K) stage(cur ^ 1, k0 + BK);
        const char* ldsA = &lds[cur][0];
        const char* ldsB = &lds[cur][0] + BM * BK * 2;
#pragma unroll
        for (int kk = 0; kk < BK; kk += 32) {
            bf16x8 af[MR], bfr[NR];
            const int clb = (kk >> 3) + lhi;
#pragma unroll
            for (int m = 0; m < MR; ++m) {
                int row = wr * WM + m * 16 + llo;
                af[m] = *(const bf16x8*)(ldsA + row * 128 + ((clb ^ (row & 7)) << 4));
            }
#pragma unroll
            for (int n = 0; n < NR; ++n) {
                int row = wc * WN + n * 16 + llo;
                bfr[n] = *(const bf16x8*)(ldsB + row * 128 + ((clb ^ (row & 7)) << 4));
            }
#pragma unroll
            for (int m = 0; m < MR; ++m)
#pragma unroll
                for (int n = 0; n < NR; ++n)
                    acc[m][n] = mfma16(af[m], bfr[n], acc[m][n]);
        }
        __syncthreads();
        cur ^= 1;
    }
#pragma unroll
    for (int m = 0; m < MR; ++m) {
        int row = m0 + wr * WM + m * 16 + lhi * 4;
#pragma unroll
        for (int n = 0; n < NR; ++n) {
            int col = n0 + wc * WN + n * 16 + llo;
            float bv = bias[col];
#pragma unroll
            for (int j = 0; j < 4; ++j)
                st_out(&C[(size_t)(row + j) * N + col], acc[m][n][j] + bv);
        }
    }
}

// ---------------- K_fuse2: RoPE q/k (bf16 QKV in) + cached K copy ----------------
__global__ void k_fuse2(const u16* __restrict__ qkv,
                        const float* __restrict__ cosT, const float* __restrict__ sinT,
                        const float* __restrict__ cached_k,
                        u16* __restrict__ qb, u16* __restrict__ kb,
                        float* __restrict__ out_k) {
    const int b = blockIdx.x;
    if (b < 4096) {
        int i = b * 256 + threadIdx.x;             // 16*1024*64
        int j = i & 63;
        int t = (i >> 6) & 1023;
        int h = i >> 16;
        const u16* row = qkv + (size_t)t * 6144;
        float q1 = bf2f(row[h * 128 + j]),        q2 = bf2f(row[h * 128 + j + 64]);
        float k1 = bf2f(row[2048 + h * 128 + j]), k2 = bf2f(row[2048 + h * 128 + j + 64]);
        float cv = cosT[t * 64 + j], sv = sinT[t * 64 + j];
        float qo1 = q1 * cv - q2 * sv, qo2 = q1 * sv + q2 * cv;
        float ko1 = k1 * cv - k2 * sv, ko2 = k1 * sv + k2 * cv;
        size_t qoff = ((size_t)h * 1024 + t) * 128 + j;
        qb[qoff] = f2bf(qo1); qb[qoff + 64] = f2bf(qo2);
        size_t koff = ((size_t)h * 2048 + 1024 + t) * 128 + j;
        kb[koff] = f2bf(ko1); kb[koff + 64] = f2bf(ko2);
        out_k[koff] = ko1; out_k[koff + 64] = ko2;
    } else {
        int i = (b - 4096) * 256 + threadIdx.x;    // 16*1024*128
        int d = i & 127, s = (i >> 7) & 1023, h = i >> 17;
        float v = cached_k[i];
        size_t off = ((size_t)h * 2048 + s) * 128 + d;
        out_k[off] = v;
        kb[off] = f2bf(v);
    }
}

// ---------------- K3c: V assemble ----------------
__global__ __launch_bounds__(256) void k_v_assemble(
    const float* __restrict__ cached_v, const u16* __restrict__ qkv,
    float* __restrict__ out_v, u16* __restrict__ vt) {
    __shared__ u16 tile[64][65];
    int s0 = blockIdx.x * 64, d0 = blockIdx.y * 64, h = blockIdx.z;
    int tid = threadIdx.x;
#pragma unroll
    for (int it = 0; it < 16; ++it) {
        int idx = it * 256 + tid;
        int r = idx >> 6, c = idx & 63;
        int s = s0 + r, d = d0 + c;
        u16 v = (s < 1024)
            ? f2bf(cached_v[((size_t)h * 1024 + s) * 128 + d])
            : qkv[(size_t)(s - 1024) * 6144 + 4096 + h * 128 + d];
        tile[r][c] = v;
        out_v[((size_t)h * 2048 + s) * 128 + d] = bf2f(v);
    }
    __syncthreads();
#pragma unroll
    for (int it = 0; it < 16; ++it) {
        int idx = it * 256 + tid;
        int dd = idx >> 6, ss = idx & 63;
        vt[((size_t)h * 128 + d0 + dd) * 2048 + s0 + ss] = tile[ss][dd];
    }
}

// ---------------- K4: flash attention, split-S, dbuf KVBLK=32, defer-max ----------------
__global__ __launch_bounds__(256, 4) void k_attn(
    const u16* __restrict__ qb,   // [16][1024][128]
    const u16* __restrict__ kb,   // [16][2048][128]
    const u16* __restrict__ vt,   // [16][128][2048]
    const float* __restrict__ bias_tab, // [16][2048]
    u16* __restrict__ Pacc,       // [1024 slots][64][128] bf16
    float* __restrict__ Pm,       // [1024 slots][64]
    float* __restrict__ Pl) {     // [1024 slots][64]
    __shared__ char ldsK[2][32 * 256];   // 8 KB each
    __shared__ char ldsV[2][128 * 64];   // 8 KB each
    __shared__ u16 ldsP[4][16 * 36];     // pitch 36 u16

    const int bid = blockIdx.x;
    const int xcd = bid & 7, idx = bid >> 3;
    const int work = xcd * 128 + idx;              // 2 heads per XCD
    const int h = work >> 6, rem = work & 63;
    const int qt = rem >> 2, chunk = rem & 3;
    const int qbase = qt * 64;
    const int tid = threadIdx.x, lane = tid & 63, wid = tid >> 6;
    const int lhi = lane >> 4, llo = lane & 15;
    const int slot = (h * 16 + qt) * 4 + chunk;

    const u16* kg = kb + (size_t)h * 2048 * 128;
    const u16* vg = vt + (size_t)h * 128 * 2048;
    const float* bt = bias_tab + h * 2048;

    bf16x8 qf[4];
    {
        const u16* qrow = qb + ((size_t)h * 1024 + qbase + wid * 16 + llo) * 128;
#pragma unroll
        for (int c = 0; c < 4; ++c)
            qf[c] = *(const bf16x8*)(qrow + c * 32 + lhi * 8);
    }

    f32x4 acc[8];
#pragma unroll
    for (int d = 0; d < 8; ++d) acc[d] = f32x4{0.f, 0.f, 0.f, 0.f};
    float mrow[4] = {-3e38f, -3e38f, -3e38f, -3e38f};
    float lrow[4] = {0.f, 0.f, 0.f, 0.f};

    const int ntiles = 34 + 2 * qt;                // 32-key tiles
    const float scale = 0.08838834764831845f;      // 1/sqrt(128)
    const int qpos = 1024 + qbase + wid * 16 + lhi * 4;

    auto stage = [&](int b, int st) {
        int sbase = st * 32;
#pragma unroll
        for (int it = 0; it < 2; ++it) {           // K: 32 rows x 16 chunks
            int ci = it * 256 + tid;
            int r = ci >> 4, c = ci & 15;
            int sc = c ^ (r & 7);
            GLD_LDS16(kg + (size_t)(sbase + r) * 128 + sc * 8,
                      &ldsK[b][0] + (it * 256 + wid * 64) * 16);
        }
#pragma unroll
        for (int it = 0; it < 2; ++it) {           // V: 128 rows x 4 chunks
            int ci = it * 256 + tid;
            int r = ci >> 2, c = ci & 3;
            int sc = c ^ ((r >> 1) & 3);
            GLD_LDS16(vg + (size_t)r * 2048 + sbase + sc * 8,
                      &ldsV[b][0] + (it * 256 + wid * 64) * 16);
        }
    };

    // descending tile order: near-diagonal (high-bias) first -> few rescales
    const int st0 = chunk + 4 * ((ntiles - 1 - chunk) >> 2);
    stage(0, st0);
    __syncthreads();
    int cur = 0;
    for (int st = st0; st >= chunk; st -= 4) {
        if (st >= chunk + 4) stage(cur ^ 1, st - 4);
        const int sbase = st * 32;
        const char* lK = &ldsK[cur][0];
        const char* lV = &ldsV[cur][0];

        // QK^T: 2 key-subtiles of 16
        f32x4 sc4[2];
        __builtin_amdgcn_s_setprio(1);
#pragma unroll
        for (int sub = 0; sub < 2; ++sub) {
            f32x4 s4 = f32x4{0.f, 0.f, 0.f, 0.f};
            int key = sub * 16 + llo;
#pragma unroll
            for (int c2 = 0; c2 < 4; ++c2) {
                int cl = c2 * 4 + lhi;
                bf16x8 kf = *(const bf16x8*)(lK + key * 256 + ((cl ^ (key & 7)) << 4));
                s4 = mfma16(qf[c2], kf, s4);
            }
            sc4[sub] = s4;
        }
        __builtin_amdgcn_s_setprio(0);

        // bias + causal mask
#pragma unroll
        for (int sub = 0; sub < 2; ++sub) {
            int key = sbase + sub * 16 + llo;
#pragma unroll
            for (int j = 0; j < 4; ++j) {
                int dist = qpos + j - key;
                float bv = bt[dist < 0 ? 0 : dist];
                sc4[sub][j] = (dist < 0) ? -3e38f : sc4[sub][j] * scale + bv;
            }
        }
        // defer-max: only reduce+rescale when a value exceeds mrow + 8
        float tmax[4];
        int ok = 1;
#pragma unroll
        for (int j = 0; j < 4; ++j) {
            tmax[j] = fmaxf(sc4[0][j], sc4[1][j]);
            ok &= (tmax[j] <= mrow[j] + 8.0f) ? 1 : 0;
        }
        if (!__all(ok)) {
#pragma unroll
            for (int j = 0; j < 4; ++j) {
                float t = tmax[j];
                t = fmaxf(t, __shfl_xor(t, 1));
                t = fmaxf(t, __shfl_xor(t, 2));
                t = fmaxf(t, __shfl_xor(t, 4));
                t = fmaxf(t, __shfl_xor(t, 8));
                float mnew = fmaxf(mrow[j], t);
                float fs = __expf(mrow[j] - mnew);
                mrow[j] = mnew;
                lrow[j] *= fs;
#pragma unroll
                for (int d = 0; d < 8; ++d) acc[d][j] *= fs;
            }
        }
        // P = exp(s - m); lrow accumulates PER-LANE partials (reduced at end)
#pragma unroll
        for (int sub = 0; sub < 2; ++sub)
#pragma unroll
            for (int j = 0; j < 4; ++j) {
                float p = __expf(sc4[sub][j] - mrow[j]);
                sc4[sub][j] = p;
                lrow[j] += p;
            }

        // P -> LDS (per-wave), then PV
        u16* P = &ldsP[wid][0];
#pragma unroll
        for (int sub = 0; sub < 2; ++sub)
#pragma unroll
            for (int j = 0; j < 4; ++j)
                P[(lhi * 4 + j) * 36 + sub * 16 + llo] = f2bf(sc4[sub][j]);

        bf16x8 pf = *(const bf16x8*)((const char*)P + llo * 72 + lhi * 16);
        __builtin_amdgcn_s_setprio(1);
#pragma unroll
        for (int db = 0; db < 8; ++db) {
            int dr = db * 16 + llo;
            int cl = lhi ^ ((dr >> 1) & 3);
            bf16x8 vf = *(const bf16x8*)(lV + dr * 64 + cl * 16);
            acc[db] = mfma16(pf, vf, acc[db]);
        }
        __builtin_amdgcn_s_setprio(0);
        __syncthreads();
        cur ^= 1;
    }

    // final sum-reduce of per-lane lrow partials across llo
#pragma unroll
    for (int j = 0; j < 4; ++j) {
        float t = lrow[j];
        t += __shfl_xor(t, 1);
        t += __shfl_xor(t, 2);
        t += __shfl_xor(t, 4);
        t += __shfl_xor(t, 8);
        lrow[j] = t;
    }

    if (llo == 0) {
#pragma unroll
        for (int j = 0; j < 4; ++j) {
            int r = wid * 16 + lhi * 4 + j;
            Pm[(size_t)slot * 64 + r] = mrow[j];
            Pl[(size_t)slot * 64 + r] = lrow[j];
        }
    }
#pragma unroll
    for (int db = 0; db < 8; ++db)
#pragma unroll
        for (int j = 0; j < 4; ++j) {
            int r = wid * 16 + lhi * 4 + j;
            Pacc[(size_t)slot * 8192 + r * 128 + db * 16 + llo] = f2bf(acc[db][j]);
        }
}

// ---------------- K4b: merge split-S partials (1024 blocks, 4/CU) ----------------
__global__ __launch_bounds__(256) void k_merge(
    const u16* __restrict__ Pacc, const float* __restrict__ Pm,
    const float* __restrict__ Pl, u16* __restrict__ yb) {
    const int b = blockIdx.x;
    const int h = b >> 6, qt = (b >> 2) & 15, quarter = b & 3;
    const int slot0 = (h * 16 + qt) * 4;
    const int tid = threadIdx.x;
    const int r = tid >> 2, dd = (tid & 3) * 8 + quarter * 32;

    float m[4], l[4];
#pragma unroll
    for (int c = 0; c < 4; ++c) {
        m[c] = Pm[(size_t)(slot0 + c) * 64 + r];
        l[c] = Pl[(size_t)(slot0 + c) * 64 + r];
    }
    float M = fmaxf(fmaxf(m[0], m[1]), fmaxf(m[2], m[3]));
    float w[4], L = 0.f;
#pragma unroll
    for (int c = 0; c < 4; ++c) {
        w[c] = __expf(m[c] - M);
        L += w[c] * l[c];
    }
    float inv = 1.0f / L;

    float y[8];
#pragma unroll
    for (int i = 0; i < 8; ++i) y[i] = 0.f;
#pragma unroll
    for (int c = 0; c < 4; ++c) {
        const uint4* pa = (const uint4*)(Pacc + (size_t)(slot0 + c) * 8192 + r * 128 + dd);
        float wc = w[c];
        uint4 v = *pa;
        u32 a[4] = {v.x, v.y, v.z, v.w};
#pragma unroll
        for (int p = 0; p < 4; ++p) {
            y[p * 2]     += wc * bf2f((u16)(a[p] & 0xFFFF));
            y[p * 2 + 1] += wc * bf2f((u16)(a[p] >> 16));
        }
    }
    int trow = qt * 64 + r;
    uint4 outv;
    u32* ow = (u32*)&outv;
#pragma unroll
    for (int k = 0; k < 4; ++k)
        ow[k] = (u32)f2bf(y[2 * k] * inv) | ((u32)f2bf(y[2 * k + 1] * inv) << 16);
    *(uint4*)(yb + (size_t)trow * 2048 + h * 128 + dd) = outv;
}

// ---------------- launch ----------------
extern "C" void kernel_launch(void* const* d_in, const int* in_sizes, int n_in,
                              void* d_out, int out_size, void* d_ws, size_t ws_size,
                              hipStream_t stream) {
    (void)in_sizes; (void)n_in; (void)out_size;
    const float* x         = (const float*)d_in[0];
    const float* cached_k  = (const float*)d_in[1];
    const float* cached_v  = (const float*)d_in[2];
    const float* W_attn    = (const float*)d_in[3];
    const float* b_attn    = (const float*)d_in[4];
    const float* W_proj    = (const float*)d_in[5];
    const float* b_proj    = (const float*)d_in[6];
    const float* decay_raw = (const float*)d_in[7];

    float* out_y = (float*)d_out;                  // 1024*2048
    float* out_k = out_y + 2097152;                // 16*2048*128
    float* out_v = out_y + 6291456;                // 16*2048*128

    char* ws = (char*)d_ws;
    if (ws_size < 63569920) return;
    // phase-1 regions
    u16*   WaT  = (u16*)(ws);                      // 6144x2048 bf16   25165824 B
    u16*   WpT  = (u16*)(ws + 25165824);           // 2048x2048 bf16    8388608 B (persists)
    u16*   Xb   = (u16*)(ws + 33554432);           // 1024x2048 bf16    4194304 B
    u16*   QKVb = (u16*)(ws + 37748736);           // 1024x6144 bf16   12582912 B
    float* BT   = (float*)(ws + 62914560);         // 16x2048 f32 (persists)
    float* CT   = (float*)(ws + 63045632);         // 1024x64 f32
    float* ST   = (float*)(ws + 63307776);         // 1024x64 f32
    // phase-2 aliases (dead regions reused)
    u16*   Qb   = (u16*)(ws);                      // in WaT   4194304 B
    u16*   Kb   = (u16*)(ws + 4194304);            // in WaT   8388608 B
    u16*   Vt   = (u16*)(ws + 12582912);           // in WaT   8388608 B
    u16*   Yb   = (u16*)(ws + 20971520);           // in WaT   4194304 B
    float* Pm   = (float*)(ws + 33554432);         // in Xb     262144 B
    float* Pl   = (float*)(ws + 33816576);         // in Xb     262144 B
    u16*   Pacc = (u16*)(ws + 37748736);           // over QKVb 16777216 B (to 54525952)

    k_prep<<<6400, 256, 0, stream>>>(W_attn, W_proj, x, decay_raw, WaT, WpT, Xb, BT, CT, ST);
    k_gemm_bt<128, 64, 2, 2, u16><<<dim3(96, 8), 256, 0, stream>>>(Xb, WaT, b_attn, QKVb, 1024, 6144, 2048);
    k_fuse2<<<12288, 256, 0, stream>>>(QKVb, CT, ST, cached_k, Qb, Kb, out_k);
    k_v_assemble<<<dim3(32, 2, 16), 256, 0, stream>>>(cached_v, QKVb, out_v, Vt);
    k_attn<<<1024, 256, 0, stream>>>(Qb, Kb, Vt, BT, Pacc, Pm, Pl);
    k_merge<<<1024, 256, 0, stream>>>(Pacc, Pm, Pl, Yb);
    k_gemm_bt<64, 64, 2, 2, float><<<dim3(32, 16), 256, 0, stream>>>(Yb, WpT, b_proj, out_y, 1024, 2048, 2048);
}